// Round 1
// baseline (496.979 us; speedup 1.0000x reference)
//
#include <hip/hip_runtime.h>
#include <stdint.h>

#define NN 8192
#define FD 256
#define LOG2E 1.44269504088896340736f
#define PPAD 136   // P_s row stride in bf16 elems (128 + 8 pad -> 272B, 16B-aligned, breaks bank conflicts)

typedef __attribute__((ext_vector_type(8))) __bf16 bf16x8;
typedef __attribute__((ext_vector_type(4))) float f32x4;

__device__ __forceinline__ unsigned short f2bf(float x) {
    unsigned u = __float_as_uint(x);
    u = u + 0x7fffu + ((u >> 16) & 1u);   // RNE; no NaNs in this problem
    return (unsigned short)(u >> 16);
}
__device__ __forceinline__ bf16x8 ld_bf8(const unsigned short* p) {
    uint4 v = *(const uint4*)p;
    return __builtin_bit_cast(bf16x8, v);
}
__device__ __forceinline__ unsigned pack2(float a, float b) {
    return (unsigned)f2bf(a) | ((unsigned)f2bf(b) << 16);
}

// ---------------- Kernel 0: WbT[f][k] = bf16(W[k][f]) ----------------
__global__ __launch_bounds__(256) void wtrans_kernel(const float* __restrict__ W,
                                                     unsigned short* __restrict__ WbT) {
    int idx = blockIdx.x * 256 + threadIdx.x;   // 65536 elems
    int k = idx >> 8, f = idx & 255;
    WbT[f * 256 + k] = f2bf(W[idx]);
}

// ---------------- Kernel 1: WhT[f][i] = bf16( (h @ W + b)[i][f] ) ----------------
// MFMA 16x16x32 bf16. Block = 256 thr (4 waves), tile = 32 rows x 256 cols, K=256.
// A-frags straight from global h (fp32 -> bf16 inline). B-frags from WbT. No K-loop LDS.
__global__ __launch_bounds__(256) void gemm1_kernel(const float* __restrict__ h,
                                                    const unsigned short* __restrict__ WbT,
                                                    const float* __restrict__ bias,
                                                    unsigned short* __restrict__ WhT) {
    __shared__ float Wh_s[256 * 33];   // [f][i] transpose bounce, +1 pad
    int t = threadIdx.x;
    int l = t & 63, w = t >> 6;
    int i0 = blockIdx.x * 32;
    int fbase = w * 64;
    int cl = l & 15, q = l >> 4;

    f32x4 acc[2][4] = {};
    const float* hA0 = h + (size_t)(i0 + cl) * FD;
    const float* hA1 = h + (size_t)(i0 + 16 + cl) * FD;

    #pragma unroll
    for (int ks = 0; ks < 8; ++ks) {
        int kk = ks * 32 + q * 8;
        union { unsigned short u[8]; bf16x8 v; } ua0, ua1;
        float4 x0 = *(const float4*)(hA0 + kk);
        float4 x1 = *(const float4*)(hA0 + kk + 4);
        float4 y0 = *(const float4*)(hA1 + kk);
        float4 y1 = *(const float4*)(hA1 + kk + 4);
        ua0.u[0]=f2bf(x0.x); ua0.u[1]=f2bf(x0.y); ua0.u[2]=f2bf(x0.z); ua0.u[3]=f2bf(x0.w);
        ua0.u[4]=f2bf(x1.x); ua0.u[5]=f2bf(x1.y); ua0.u[6]=f2bf(x1.z); ua0.u[7]=f2bf(x1.w);
        ua1.u[0]=f2bf(y0.x); ua1.u[1]=f2bf(y0.y); ua1.u[2]=f2bf(y0.z); ua1.u[3]=f2bf(y0.w);
        ua1.u[4]=f2bf(y1.x); ua1.u[5]=f2bf(y1.y); ua1.u[6]=f2bf(y1.z); ua1.u[7]=f2bf(y1.w);
        #pragma unroll
        for (int bg = 0; bg < 4; ++bg) {
            bf16x8 bF = ld_bf8(WbT + (fbase + bg * 16 + cl) * 256 + kk);
            acc[0][bg] = __builtin_amdgcn_mfma_f32_16x16x32_bf16(ua0.v, bF, acc[0][bg], 0, 0, 0);
            acc[1][bg] = __builtin_amdgcn_mfma_f32_16x16x32_bf16(ua1.v, bF, acc[1][bg], 0, 0, 0);
        }
    }

    // C layout: col = lane&15, row = (lane>>4)*4 + reg   [m89-verified]
    #pragma unroll
    for (int mt = 0; mt < 2; ++mt)
        #pragma unroll
        for (int bg = 0; bg < 4; ++bg)
            #pragma unroll
            for (int e = 0; e < 4; ++e) {
                int il = mt * 16 + q * 4 + e;
                int fl = fbase + bg * 16 + cl;
                Wh_s[fl * 33 + il] = acc[mt][bg][e] + bias[fl];
            }
    __syncthreads();
    {   // thread t owns f-row t; write 32 bf16 (i-contig) as 4x uint4
        const float* src = &Wh_s[t * 33];
        unsigned short* dst = WhT + (size_t)t * NN + i0;
        #pragma unroll
        for (int ig = 0; ig < 4; ++ig) {
            union { unsigned short u[8]; uint4 v; } p;
            #pragma unroll
            for (int e = 0; e < 8; ++e) p.u[e] = f2bf(src[ig * 8 + e]);
            *(uint4*)(dst + ig * 8) = p.v;
        }
    }
}

// ---------------- Kernel 2: f1p[i] = log2e * sum_f WhT[f][i]*a1[f]; same for f2p ----------------
__global__ __launch_bounds__(256) void f1f2_kernel(const unsigned short* __restrict__ WhT,
                                                   const float* __restrict__ a,
                                                   float* __restrict__ f1p,
                                                   float* __restrict__ f2p) {
    int i = blockIdx.x * 256 + threadIdx.x;
    float s1 = 0.f, s2 = 0.f;
    #pragma unroll 8
    for (int f = 0; f < 256; ++f) {
        float wv = __uint_as_float((unsigned)WhT[(size_t)f * NN + i] << 16);
        s1 += wv * a[f];
        s2 += wv * a[256 + f];
    }
    f1p[i] = s1 * LOG2E;
    f2p[i] = s2 * LOG2E;
}

// ---------------- Kernel 3: fused masked-softmax attention x Wh ----------------
// Block = 512 thr (8 waves), 32 output rows, K-loop over j in chunks of 128.
// waves: ns = w&3 -> 64-col slice; kh = w>>2 -> k-half (K split 2-way, LDS-reduced in epilogue).
__global__ __launch_bounds__(512, 2) void gat_kernel(const int* __restrict__ adj,
                                                     const unsigned short* __restrict__ WhT,
                                                     const float* __restrict__ f1p,
                                                     const float* __restrict__ f2p,
                                                     float* __restrict__ out) {
    __shared__ float rowsum_s[32];
    __shared__ unsigned short P_s[32 * PPAD];
    __shared__ float red_s[32 * 256];

    int t = threadIdx.x;
    int l = t & 63, w = t >> 6;
    int i0 = blockIdx.x * 32;
    if (t < 32) rowsum_s[t] = 0.f;

    // P-compute mapping: 512 thr x 2 passes cover 32 rows x 128 cols, 4 cols/thread
    int pr = t >> 5;            // 0..15
    int pc = (t & 31) * 4;      // 0..124
    float f1v0 = f1p[i0 + pr];
    float f1v1 = f1p[i0 + 16 + pr];

    // MFMA mapping
    int ns = w & 3, kh = w >> 2;
    int fbase = ns * 64;
    int cl = l & 15, q = l >> 4;
    f32x4 acc[2][4] = {};
    const unsigned short* wrow = WhT + (size_t)(fbase + cl) * NN;

    // prefetch adj/f2 for iter 0
    const int* aprow = adj + (size_t)(i0 + pr) * NN + pc;
    int4 adjv0 = *(const int4*)(aprow);
    int4 adjv1 = *(const int4*)(aprow + (size_t)16 * NN);
    float4 f2v = *(const float4*)(f2p + pc);

    for (int jt = 0; jt < NN / 128; ++jt) {
        int j0 = jt * 128;
        int4 a0 = adjv0, a1 = adjv1;
        float4 fv = f2v;
        if (jt < NN / 128 - 1) {   // prefetch next chunk (full iteration of latency cover)
            adjv0 = *(const int4*)(aprow + j0 + 128);
            adjv1 = *(const int4*)(aprow + (size_t)16 * NN + j0 + 128);
            f2v = *(const float4*)(f2p + j0 + 128 + pc);
        }
        float ws0[4], ws1[4], rs0 = 0.f, rs1 = 0.f;
        {
            float fe[4] = {fv.x, fv.y, fv.z, fv.w};
            int ae0[4] = {a0.x, a0.y, a0.z, a0.w};
            int ae1[4] = {a1.x, a1.y, a1.z, a1.w};
            #pragma unroll
            for (int e = 0; e < 4; ++e) {
                float s0 = f1v0 + fe[e]; s0 = fmaxf(s0, 0.2f * s0);
                float w0 = exp2f(s0); w0 = ae0[e] > 0 ? w0 : 0.f;
                ws0[e] = w0; rs0 += w0;
                float s1 = f1v1 + fe[e]; s1 = fmaxf(s1, 0.2f * s1);
                float w1 = exp2f(s1); w1 = ae1[e] > 0 ? w1 : 0.f;
                ws1[e] = w1; rs1 += w1;
            }
        }
        #pragma unroll
        for (int m = 1; m <= 16; m <<= 1) { rs0 += __shfl_xor(rs0, m); rs1 += __shfl_xor(rs1, m); }

        __syncthreads();   // A: previous iter's MFMA reads of P_s are done
        *(uint2*)(P_s + pr * PPAD + pc) = make_uint2(pack2(ws0[0], ws0[1]), pack2(ws0[2], ws0[3]));
        *(uint2*)(P_s + (16 + pr) * PPAD + pc) = make_uint2(pack2(ws1[0], ws1[1]), pack2(ws1[2], ws1[3]));
        if ((l & 31) == 0) { atomicAdd(&rowsum_s[pr], rs0); atomicAdd(&rowsum_s[16 + pr], rs1); }
        __syncthreads();   // B: P_s ready

        #pragma unroll
        for (int ksi = 0; ksi < 2; ++ksi) {
            int kk = kh * 64 + ksi * 32 + q * 8;
            bf16x8 af0 = ld_bf8(P_s + cl * PPAD + kk);
            bf16x8 af1 = ld_bf8(P_s + (16 + cl) * PPAD + kk);
            #pragma unroll
            for (int bg = 0; bg < 4; ++bg) {
                bf16x8 bF = ld_bf8(wrow + (size_t)bg * 16 * NN + j0 + kk);
                acc[0][bg] = __builtin_amdgcn_mfma_f32_16x16x32_bf16(af0, bF, acc[0][bg], 0, 0, 0);
                acc[1][bg] = __builtin_amdgcn_mfma_f32_16x16x32_bf16(af1, bF, acc[1][bg], 0, 0, 0);
            }
        }
    }

    __syncthreads();
    if (kh == 1) {
        #pragma unroll
        for (int mt = 0; mt < 2; ++mt)
            #pragma unroll
            for (int bg = 0; bg < 4; ++bg)
                #pragma unroll
                for (int e = 0; e < 4; ++e)
                    red_s[(mt * 16 + q * 4 + e) * 256 + fbase + bg * 16 + cl] = acc[mt][bg][e];
    }
    __syncthreads();
    if (kh == 0) {
        #pragma unroll
        for (int mt = 0; mt < 2; ++mt)
            #pragma unroll
            for (int e = 0; e < 4; ++e) {
                int row = mt * 16 + q * 4 + e;
                float inv = 1.0f / rowsum_s[row];
                #pragma unroll
                for (int bg = 0; bg < 4; ++bg) {
                    float v = acc[mt][bg][e] + red_s[row * 256 + fbase + bg * 16 + cl];
                    out[(size_t)(i0 + row) * FD + fbase + bg * 16 + cl] = v * inv;
                }
            }
    }
}

extern "C" void kernel_launch(void* const* d_in, const int* in_sizes, int n_in,
                              void* d_out, int out_size, void* d_ws, size_t ws_size,
                              hipStream_t stream) {
    const float* h   = (const float*)d_in[0];
    const int*   adj = (const int*)d_in[1];
    const float* W   = (const float*)d_in[2];
    const float* b   = (const float*)d_in[3];
    const float* a   = (const float*)d_in[4];
    float* out = (float*)d_out;

    char* ws = (char*)d_ws;
    unsigned short* WhT = (unsigned short*)ws;                        // 256 x 8192 bf16 = 4 MB
    unsigned short* WbT = (unsigned short*)(ws + 4 * 1024 * 1024);    // 256 x 256 bf16 = 128 KB
    float* f1p = (float*)(ws + 4 * 1024 * 1024 + 128 * 1024);         // 8192 f32
    float* f2p = f1p + NN;                                            // 8192 f32

    wtrans_kernel<<<256, 256, 0, stream>>>(W, WbT);
    gemm1_kernel<<<256, 256, 0, stream>>>(h, WbT, b, WhT);
    f1f2_kernel<<<32, 256, 0, stream>>>(WhT, a, f1p, f2p);
    gat_kernel<<<256, 512, 0, stream>>>(adj, WhT, f1p, f2p, out);
}